// Round 3
// baseline (258.022 us; speedup 1.0000x reference)
//
#include <hip/hip_runtime.h>
#include <math.h>

#define BB   512
#define NN   512
#define MM   128
#define CC   1024
#define ADDR 134
#define EPSF 1e-8f
#define WSSTRIDE 136   // per-b: 128 k + 8 params

__device__ __forceinline__ float softplus_f(float x) {
    return fmaxf(x, 0.0f) + log1pf(expf(-fabsf(x)));
}

// ---------------- kernel 1: fc + derived scalar params ----------------
// grid 256, block 192. Block handles b0=2*bid, b0+1. Thread j<134 computes
// out[b][j] for both b's (2 FMAs per W load). Params + k -> ws.
__global__ __launch_bounds__(192) void ntm_fc_kernel(
    const float* __restrict__ co,     // B x C
    const float* __restrict__ W_fc,   // C x ADDR
    const float* __restrict__ b_fc,   // ADDR
    float* __restrict__ ws)           // B x WSSTRIDE
{
    __shared__ __align__(16) float s_co[2 * CC];
    __shared__ float s_nr[2][2];
    __shared__ float s_ex[2][8];

    const int t = threadIdx.x;
    const int b0 = blockIdx.x * 2;

    // stage both controller rows (contiguous 2048 floats)
    {
        const float4* src = (const float4*)(co + (size_t)b0 * CC);
        float4* dst = (float4*)s_co;
        for (int i = t; i < 512; i += 192) dst[i] = src[i];
    }
    __syncthreads();

    float k0 = 0.f, k1 = 0.f;
    if (t < ADDR) {
        float a00 = 0.f, a01 = 0.f, a10 = 0.f, a11 = 0.f;
        const float* Wj = W_fc + t;
        for (int c = 0; c < CC; c += 8) {
            float wv[8];
            #pragma unroll
            for (int i = 0; i < 8; ++i) wv[i] = Wj[(size_t)(c + i) * ADDR];
            #pragma unroll
            for (int i = 0; i < 8; ++i) {
                if (i & 1) { a01 = fmaf(wv[i], s_co[c + i], a01);
                             a11 = fmaf(wv[i], s_co[CC + c + i], a11); }
                else       { a00 = fmaf(wv[i], s_co[c + i], a00);
                             a10 = fmaf(wv[i], s_co[CC + c + i], a10); }
            }
        }
        float bias = b_fc[t];
        k0 = a00 + a01 + bias;
        k1 = a10 + a11 + bias;
        if (t >= MM) { s_ex[0][t - MM] = k0; s_ex[1][t - MM] = k1; }
        else {
            ws[(size_t)b0 * WSSTRIDE + t] = k0;
            ws[(size_t)(b0 + 1) * WSSTRIDE + t] = k1;
        }
    }
    // norm reduction over j<128 (waves 0 and 1)
    if (t < MM) {
        float v0 = k0 * k0, v1 = k1 * k1;
        #pragma unroll
        for (int off = 32; off >= 1; off >>= 1) {
            v0 += __shfl_xor(v0, off, 64);
            v1 += __shfl_xor(v1, off, 64);
        }
        if ((t & 63) == 0) { s_nr[t >> 6][0] = v0; s_nr[t >> 6][1] = v1; }
    }
    __syncthreads();
    if (t < 2) {
        float ks = s_nr[0][t] + s_nr[1][t];
        float norm_k = sqrtf(ks) + EPSF;
        float beta = softplus_f(s_ex[t][0]);
        float g = 1.0f / (1.0f + expf(-s_ex[t][1]));
        float e0 = s_ex[t][2], e1 = s_ex[t][3], e2 = s_ex[t][4];
        float mx = fmaxf(e0, fmaxf(e1, e2));
        float x0 = expf(e0 - mx), x1 = expf(e1 - mx), x2 = expf(e2 - mx);
        float inv = 1.0f / (x0 + x1 + x2);
        float* p = ws + (size_t)(b0 + t) * WSSTRIDE + MM;
        p[0] = beta / norm_k;
        p[1] = g;
        p[2] = x0 * inv;
        p[3] = x1 * inv;
        p[4] = x2 * inv;
        p[5] = 1.0f + softplus_f(s_ex[t][5]);
    }
}

// ---------------- kernel 2: sim -> softmax -> gate/shift/sharpen -> read ----
__global__ __launch_bounds__(1024) void ntm_main_kernel(
    const float* __restrict__ prev_w,  // B x N
    const float* __restrict__ mem,     // B x N x M
    const float* __restrict__ ws,      // B x WSSTRIDE
    float* __restrict__ out_rv,        // B x M
    float* __restrict__ out_w)         // B x N
{
    __shared__ __align__(16) float s_k[MM];
    __shared__ float s_params[8];
    __shared__ float s_bsim[NN];
    __shared__ float s_wg[NN];
    __shared__ float s_w[NN];
    __shared__ __align__(16) float s_part[32 * MM];
    __shared__ float s_redA[16];
    __shared__ float s_redB[16];

    const int t = threadIdx.x;
    const int b = blockIdx.x;
    const int wv = t >> 6;

    // early prefetch of prev_w
    float pw = (t < NN) ? prev_w[(size_t)b * NN + t] : 0.0f;

    if (t < WSSTRIDE) {
        float v = ws[(size_t)b * WSSTRIDE + t];
        if (t < MM) s_k[t] = v; else s_params[t - MM] = v;
    }
    __syncthreads();

    const float bnk = s_params[0];
    const float4* memb = (const float4*)(mem + (size_t)b * NN * MM);

    // ---- pass 1: 4 lanes per row, 8 float4 per lane ----
    {
        const int l4 = t & 3;
        const int row0 = t >> 2;                 // 0..255
        float4 kf[8];
        #pragma unroll
        for (int i = 0; i < 8; ++i) kf[i] = ((const float4*)s_k)[l4 + 4 * i];

        float maxv = -INFINITY;
        #pragma unroll
        for (int it = 0; it < 2; ++it) {
            const int row = row0 + it * 256;
            const float4* rp = memb + (size_t)row * 32;
            float4 a[8];
            #pragma unroll
            for (int i = 0; i < 8; ++i) a[i] = rp[l4 + 4 * i];
            float d = 0.f, q = 0.f;
            #pragma unroll
            for (int i = 0; i < 8; ++i) {
                d = fmaf(a[i].x, kf[i].x, d); q = fmaf(a[i].x, a[i].x, q);
                d = fmaf(a[i].y, kf[i].y, d); q = fmaf(a[i].y, a[i].y, q);
                d = fmaf(a[i].z, kf[i].z, d); q = fmaf(a[i].z, a[i].z, q);
                d = fmaf(a[i].w, kf[i].w, d); q = fmaf(a[i].w, a[i].w, q);
            }
            d += __shfl_xor(d, 1, 64); q += __shfl_xor(q, 1, 64);
            d += __shfl_xor(d, 2, 64); q += __shfl_xor(q, 2, 64);
            float bsim = bnk * d / (sqrtf(q) + EPSF);
            maxv = fmaxf(maxv, bsim);
            if (l4 == 0) s_bsim[row] = bsim;
        }
        // block max
        #pragma unroll
        for (int off = 32; off >= 1; off >>= 1) maxv = fmaxf(maxv, __shfl_xor(maxv, off, 64));
        if ((t & 63) == 0) s_redA[wv] = maxv;
    }
    __syncthreads();

    float Mx = -INFINITY;
    #pragma unroll
    for (int i = 0; i < 16; ++i) Mx = fmaxf(Mx, s_redA[i]);

    // ---- softmax + gate + shift + sharpen + normalize ----
    {
        const bool act = (t < NN);
        float e = act ? expf(s_bsim[t] - Mx) : 0.0f;
        float ls = e;
        #pragma unroll
        for (int off = 32; off >= 1; off >>= 1) ls += __shfl_xor(ls, off, 64);
        if ((t & 63) == 0) s_redB[wv] = ls;
        __syncthreads();
        float S = 0.f;
        #pragma unroll
        for (int i = 0; i < 16; ++i) S += s_redB[i];

        const float invS = 1.0f / S;
        const float g = s_params[1];
        float wg = 0.0f;
        if (act) { wg = fmaf(g, e * invS, (1.0f - g) * pw); s_wg[t] = wg; }
        __syncthreads();

        float wp = 0.0f;
        if (act) {
            float wsv = s_params[2] * s_wg[(t + NN - 1) & (NN - 1)]
                      + s_params[3] * wg
                      + s_params[4] * s_wg[(t + 1) & (NN - 1)];
            wp = powf(wsv, s_params[5]);
        }
        float lz = wp;
        #pragma unroll
        for (int off = 32; off >= 1; off >>= 1) lz += __shfl_xor(lz, off, 64);
        if ((t & 63) == 0) s_redA[wv] = lz;
        __syncthreads();
        float Z = 0.f;
        #pragma unroll
        for (int i = 0; i < 16; ++i) Z += s_redA[i];

        if (act) {
            float w = wp / (Z + EPSF);
            s_w[t] = w;
            out_w[(size_t)b * NN + t] = w;
        }
    }
    __syncthreads();

    // ---- pass 2: read_vec = w @ mem; 32 groups x 16 rows ----
    {
        const int q = t >> 5;
        const int l = t & 31;
        float4 acc = make_float4(0.f, 0.f, 0.f, 0.f);
        const int nb = q * 16;
        #pragma unroll
        for (int i = 0; i < 16; i += 4) {
            const int n = nb + i;
            float4 a0 = memb[(size_t)(n    ) * 32 + l];
            float4 a1 = memb[(size_t)(n + 1) * 32 + l];
            float4 a2 = memb[(size_t)(n + 2) * 32 + l];
            float4 a3 = memb[(size_t)(n + 3) * 32 + l];
            float w0 = s_w[n], w1 = s_w[n + 1], w2 = s_w[n + 2], w3 = s_w[n + 3];
            acc.x = fmaf(w0, a0.x, acc.x); acc.y = fmaf(w0, a0.y, acc.y);
            acc.z = fmaf(w0, a0.z, acc.z); acc.w = fmaf(w0, a0.w, acc.w);
            acc.x = fmaf(w1, a1.x, acc.x); acc.y = fmaf(w1, a1.y, acc.y);
            acc.z = fmaf(w1, a1.z, acc.z); acc.w = fmaf(w1, a1.w, acc.w);
            acc.x = fmaf(w2, a2.x, acc.x); acc.y = fmaf(w2, a2.y, acc.y);
            acc.z = fmaf(w2, a2.z, acc.z); acc.w = fmaf(w2, a2.w, acc.w);
            acc.x = fmaf(w3, a3.x, acc.x); acc.y = fmaf(w3, a3.y, acc.y);
            acc.z = fmaf(w3, a3.z, acc.z); acc.w = fmaf(w3, a3.w, acc.w);
        }
        *((float4*)&s_part[q * MM + l * 4]) = acc;
        __syncthreads();
        if (t < MM) {
            float r = 0.f;
            #pragma unroll
            for (int q2 = 0; q2 < 32; ++q2) r += s_part[q2 * MM + t];
            out_rv[(size_t)b * MM + t] = r;
        }
    }
}

extern "C" void kernel_launch(void* const* d_in, const int* in_sizes, int n_in,
                              void* d_out, int out_size, void* d_ws, size_t ws_size,
                              hipStream_t stream) {
    const float* co     = (const float*)d_in[0];
    const float* prev_w = (const float*)d_in[1];
    const float* mem    = (const float*)d_in[2];
    const float* W_fc   = (const float*)d_in[3];
    const float* b_fc   = (const float*)d_in[4];
    float* out = (float*)d_out;
    float* ws  = (float*)d_ws;

    ntm_fc_kernel<<<BB / 2, 192, 0, stream>>>(co, W_fc, b_fc, ws);
    ntm_main_kernel<<<BB, 1024, 0, stream>>>(prev_w, mem, ws,
                                             out, out + (size_t)BB * MM);
}